// Round 1
// 278.453 us; speedup vs baseline: 1.0370x; 1.0370x over previous
//
#include <hip/hip_runtime.h>
#include <math.h>

#define VIEWS 512
#define DETS  512

typedef float f32x4 __attribute__((ext_vector_type(4)));
typedef float f32x2 __attribute__((ext_vector_type(2)));

// derived constants (double, folded at compile time)
constexpr double S2R_D    = 5.95;
constexpr double D2R_D    = 4.906;
constexpr double DDET_D   = 0.0072;
constexpr double VIRDET_D = DDET_D * S2R_D / (S2R_D + D2R_D);
constexpr double DANG_D   = 2.0 * 3.14159265358979323846 / (double)VIEWS;
constexpr double DIMG_D   = 0.006641;

// ---------------------------------------------------------------------------
// Fused kernel: one block per view.
//   phase 0: zero pads, stage filter taps + proj*w rows (both batches) in LDS
//   phase 1: ramp filter (even-tap trimmed scheme) -> zero-padded interleaved
//            LDS row pair rows01[det -128..639][batch 0..1]
//   phase 2: backprojection of the full 2x256x256 slab for this view.
//            Zero-padding makes bounds masks/clamps unnecessary:
//            |u| <= 5.95*1.1974/4.7526 -> t+128 in [3.0, 763.5], i1 <= 764.
// ---------------------------------------------------------------------------
__global__ __launch_bounds__(256) void fbp_fused_kernel(
    const float* __restrict__ proj, const float* __restrict__ wq,
    const float* __restrict__ filt, float* __restrict__ out)
{
    __shared__ __align__(16) float pwpad[2][1536];   // padded proj*w rows
    __shared__ __align__(16) float sfe[520];         // even-index taps (odd x)
    __shared__ __align__(16) float rows01[1536];     // {r0,r1} interleaved, det -128..639

    const int tid = threadIdx.x;
    const int v   = blockIdx.x;                      // view

    const float beta = (float)DANG_D * (float)v;
    const float cb = cosf(beta);
    const float sb = sinf(beta);

    {   // phase 0a: zero-init pads + stage taps
        const f32x4 z = {0.f, 0.f, 0.f, 0.f};
        f32x4* pz = (f32x4*)&pwpad[0][0];            // 768 f32x4
        #pragma unroll
        for (int i = 0; i < 3; ++i) pz[tid + 256*i] = z;
        f32x4* rz = (f32x4*)rows01;                  // 384 f32x4
        rz[tid] = z;
        if (tid < 128) rz[256 + tid] = z;
        for (int i = tid; i < 520; i += 256)
            sfe[i] = (i < 512) ? filt[2*i] : 0.0f;
    }
    __syncthreads();

    {   // phase 0b: stage proj rows * w (128 threads per row; rows = {v, 512+v})
        const int rl  = tid >> 7;
        const int t2  = tid & 127;
        const int row = rl * VIEWS + v;              // batch-major row index
        const f32x4 p4 = *(const f32x4*)(proj + ((size_t)row << 9) + 4*t2);
        const f32x4 w4 = *(const f32x4*)(wq + 4*t2);
        pwpad[rl][511 + 4*t2 + 0] = p4.x * w4.x;
        pwpad[rl][511 + 4*t2 + 1] = p4.y * w4.y;
        pwpad[rl][511 + 4*t2 + 2] = p4.z * w4.z;
        pwpad[rl][511 + 4*t2 + 3] = p4.w * w4.w;
    }
    __syncthreads();

    const int lane = tid & 63;
    const int warp = tid >> 6;                       // 0..3

    {   // phase 1: ramp filter. warp -> (row = warp>>1, half = warp&1)
        const int rl2 = warp >> 1;
        const int wv  = warp & 1;
        const int d0  = 256*wv + 4*lane;             // first of 4 outputs
        const float* P = &pwpad[rl2][0];
        const int e_lo = wv ? 0 : 124;               // trimmed even-tap range
        const int G    = wv ? 48 : 49;
        const float c0 = filt[511];                  // center tap
        float a0=0.f, a1=0.f, a2=0.f, a3=0.f;
        for (int g = 0; g < G; ++g) {
            const int e0 = e_lo + 8*g;
            const f32x4 S0 = *(const f32x4*)&sfe[e0];      // wave-uniform broadcast
            const f32x4 S1 = *(const f32x4*)&sfe[e0 + 4];
            const float* Pb = P + d0 + 2*e0;               // 16B aligned
            const f32x4 q0 = *(const f32x4*)(Pb + 0);
            const f32x4 q1 = *(const f32x4*)(Pb + 4);
            const f32x4 q2 = *(const f32x4*)(Pb + 8);
            const f32x4 q3 = *(const f32x4*)(Pb + 12);
            const f32x4 q4 = *(const f32x4*)(Pb + 16);
            const float p[20] = {q0.x,q0.y,q0.z,q0.w, q1.x,q1.y,q1.z,q1.w,
                                 q2.x,q2.y,q2.z,q2.w, q3.x,q3.y,q3.z,q3.w,
                                 q4.x,q4.y,q4.z,q4.w};
            const float s[8]  = {S0.x,S0.y,S0.z,S0.w, S1.x,S1.y,S1.z,S1.w};
            #pragma unroll
            for (int j = 0; j < 8; ++j) {
                a0 = fmaf(p[2*j + 0], s[j], a0);
                a1 = fmaf(p[2*j + 1], s[j], a1);
                a2 = fmaf(p[2*j + 2], s[j], a2);
                a3 = fmaf(p[2*j + 3], s[j], a3);
            }
        }
        a0 = fmaf(P[511 + d0 + 0], c0, a0);
        a1 = fmaf(P[511 + d0 + 1], c0, a1);
        a2 = fmaf(P[511 + d0 + 2], c0, a2);
        a3 = fmaf(P[511 + d0 + 3], c0, a3);
        // write interleaved {row0[d], row1[d]} at det offset +128
        float* W = &rows01[((128 + d0) << 1) + rl2];
        W[0] = a0; W[2] = a1; W[4] = a2; W[6] = a3;
    }
    __syncthreads();

    {   // phase 2: backprojection, whole view slab. warp = y offset in groups of 4.
        const float D    = (float)DIMG_D;
        const float Kf   = (float)(S2R_D / VIRDET_D);    // 5.95/VIRDET
        const int   xi   = 4*lane;
        const float xs0  = ((float)xi - 127.5f) * D;
        const float xc0  = xs0 * cb;
        const float xsbK = (xs0 * sb) * Kf;
        const float dcb  = D * cb;
        const float dsbK = (D * sb) * Kf;
        const f32x2* R2  = (const f32x2*)rows01;
        f32x4* o0p = (f32x4*)(out + ((size_t)v << 16));

        #pragma unroll 2
        for (int i = 0; i < 64; ++i) {
            const int   y   = 4*i + warp;                 // wave-uniform
            const float ys  = (127.5f - (float)y) * D;
            const float ysb = ys * sb;
            const float ycb = ys * cb;
            const float dbase = (5.95f - ysb) - xc0;      // den_j = dbase - j*dcb
            const float nbase = fmaf(Kf, ycb, -xsbK);     // num'_j = nbase - j*dsbK
            f32x4 o0, o1;
            #pragma unroll
            for (int j = 0; j < 4; ++j) {
                const float jf  = (float)j;
                const float den = fmaf(jf, -dcb,  dbase);
                const float num = fmaf(jf, -dsbK, nbase);
                float inv = __builtin_amdgcn_rcpf(den);
                inv = inv * fmaf(-den, inv, 2.0f);        // 1 Newton step
                const float wgt = 35.4025f * (inv * inv); // (5.95/den)^2
                const float t   = fmaf(num, inv, 383.5f); // 255.5 + 128 pad shift
                const float ft  = floorf(t);
                const float fr  = t - ft;
                const int   idx = (int)ft;                // in [3, 763]
                const f32x2 ab  = R2[idx];                // {r0[i0], r1[i0]}
                const f32x2 cd  = R2[idx + 1];            // {r0[i1], r1[i1]}
                o0[j] = wgt * fmaf(fr, cd.x - ab.x, ab.x);
                o1[j] = wgt * fmaf(fr, cd.y - ab.y, ab.y);
            }
            const size_t p4i = ((size_t)y << 6) + (size_t)lane;
            __builtin_nontemporal_store(o0, o0p + p4i);
            __builtin_nontemporal_store(o1, o0p + 8388608u + p4i);  // batch 1
        }
    }
}

extern "C" void kernel_launch(void* const* d_in, const int* in_sizes, int n_in,
                              void* d_out, int out_size, void* d_ws, size_t ws_size,
                              hipStream_t stream) {
    const float* proj = (const float*)d_in[0];   // (2,1,512,512)
    const float* wq   = (const float*)d_in[1];   // (512,)
    const float* filt = (const float*)d_in[2];   // (1023,)
    float* out = (float*)d_out;                  // (2,512,256,256)
    (void)in_sizes; (void)n_in; (void)out_size; (void)d_ws; (void)ws_size;

    hipLaunchKernelGGL(fbp_fused_kernel, dim3(VIEWS), dim3(256), 0, stream,
                       proj, wq, filt, out);
}